// Round 9
// baseline (146.458 us; speedup 1.0000x reference)
//
#include <hip/hip_runtime.h>

constexpr int EMB_DIM   = 300;
constexpr int HIDDEN    = 256;
constexpr int OUT_DIM   = 3;
constexpr int SEQ       = 128;
constexpr int N_ASPECTS = 8;
constexpr int TILE      = 32;    // bucket padding granularity
constexpr int MTILE     = 16;    // samples per MLP block (2 groups x 8)

// ---------------------------------------------------------------------------
// bf16 helpers (RNE)
// ---------------------------------------------------------------------------
__device__ __forceinline__ unsigned int bfbits(float f) {
  unsigned int u = __float_as_uint(f);
  return (u + 0x7fffu + ((u >> 16) & 1u)) >> 16;
}
__device__ __forceinline__ unsigned int pack2(float lo, float hi) {
  return bfbits(lo) | (bfbits(hi) << 16);
}
__device__ __forceinline__ float blo(unsigned int u) { return __uint_as_float(u << 16); }
__device__ __forceinline__ float bhi(unsigned int u) { return __uint_as_float(u & 0xffff0000u); }

// ---------------------------------------------------------------------------
// Fused prep: block 0 = deterministic counting-sort bucketing (pad to TILE,
// -1 = padding); blocks 1..N = fp32->bf16 table conversion (90 MB stream).
// ---------------------------------------------------------------------------
__global__ __launch_bounds__(1024) void prep_kernel(
    const float* __restrict__ emb, unsigned int* __restrict__ emb16, int n8,
    const int* __restrict__ aspect, int B, int* __restrict__ perm, int nperm) {
  const int t = threadIdx.x;

  if (blockIdx.x != 0) {
    int i = (blockIdx.x - 1) * 1024 + t;
    const int stride = (gridDim.x - 1) * 1024;
    for (; i < n8; i += stride) {
      const float4* p = (const float4*)emb + (size_t)i * 2;
      float4 a = p[0], b = p[1];
      uint4 o;
      o.x = pack2(a.x, a.y); o.y = pack2(a.z, a.w);
      o.z = pack2(b.x, b.y); o.w = pack2(b.z, b.w);
      ((uint4*)emb16)[i] = o;
    }
    return;
  }

  const int lane = t & 63, wave = t >> 6;          // 16 waves
  __shared__ int wcnt[16][N_ASPECTS];
  __shared__ int cur[16][N_ASPECTS];

  for (int i = t; i < nperm; i += 1024) perm[i] = -1;

  int my_a[8];
  int cnt[N_ASPECTS];
#pragma unroll
  for (int q = 0; q < N_ASPECTS; ++q) cnt[q] = 0;
#pragma unroll
  for (int k = 0; k < 8; ++k) {
    int s = t + k * 1024;
    int a = (s < B) ? aspect[s] : -1;
    my_a[k] = a;
#pragma unroll
    for (int q = 0; q < N_ASPECTS; ++q) cnt[q] += (a == q);
  }
#pragma unroll
  for (int q = 0; q < N_ASPECTS; ++q) {
    int c = cnt[q];
    for (int off = 32; off > 0; off >>= 1) c += __shfl_down(c, off);
    if (lane == 0) wcnt[wave][q] = c;
  }
  __syncthreads();
  if (t == 0) {
    int base = 0;
    for (int q = 0; q < N_ASPECTS; ++q) {
      int tot = 0;
      for (int w = 0; w < 16; ++w) { cur[w][q] = base + tot; tot += wcnt[w][q]; }
      base += ((tot + TILE - 1) / TILE) * TILE;
    }
  }
  __syncthreads();

#pragma unroll
  for (int k = 0; k < 8; ++k) {
    int a = my_a[k];
    int s = t + k * 1024;
#pragma unroll
    for (int q = 0; q < N_ASPECTS; ++q) {
      unsigned long long m = __ballot(a == q);
      if (a == q) {
        int rank = __popcll(m & ((1ull << lane) - 1ull));
        int pos = cur[wave][q] + rank;
        perm[pos] = s;
        if (rank == __popcll(m) - 1) cur[wave][q] = pos + 1;
      }
    }
  }
}

// ---------------------------------------------------------------------------
// Pool, vocab-windowed: one sample per wave; bitonic-sort the 128 ids
// (regs + shfl), then process ONLY ids in [lo,hi) this pass (range found via
// ballot popcount on the sorted regs). Two dispatches sweep half the table
// each: 15 MB window -> L2/L3-resident; the dispatch boundary re-tightens
// the convoy. Sort bugs can only cost locality, never correctness.
// ---------------------------------------------------------------------------
__global__ __launch_bounds__(256) void pool_kernel(
    const int* __restrict__ ids, const unsigned short* __restrict__ emb16,
    float* __restrict__ x, int B, int lo, int hi, int first) {
  const int wave = threadIdx.x >> 6, lane = threadIdx.x & 63;
  const int b = blockIdx.x * 4 + wave;
  if (b >= B) return;

  int r0 = ids[(size_t)b * SEQ + lane];
  int r1 = ids[(size_t)b * SEQ + lane + 64];

#pragma unroll
  for (int k = 2; k <= 128; k <<= 1) {
#pragma unroll
    for (int j = k >> 1; j >= 1; j >>= 1) {
      if (j == 64) {
        int t0 = min(r0, r1), t1 = max(r0, r1);
        r0 = t0; r1 = t1;
      } else {
        const bool up0 = ((lane & k) == 0);
        const bool up1 = (((lane + 64) & k) == 0);
        const bool side = ((lane & j) == 0);
        int o0 = __shfl_xor(r0, j);
        int o1 = __shfl_xor(r1, j);
        r0 = (side == up0) ? min(r0, o0) : max(r0, o0);
        r1 = (side == up1) ? min(r1, o1) : max(r1, o1);
      }
    }
  }

  // this wave's token range for [lo,hi): sorted order is sid[0..127]
  const int s0 = __popcll(__ballot(r0 < lo)) + __popcll(__ballot(r1 < lo));
  const int s1 = __popcll(__ballot(r0 < hi)) + __popcll(__ballot(r1 < hi));

  __shared__ int sid[4][SEQ];
  sid[wave][lane]      = r0;
  sid[wave][lane + 64] = r1;
  __syncthreads();

  float a0 = 0.f, a1 = 0.f, a2 = 0.f, a3 = 0.f;
  float c0 = 0.f, c1 = 0.f, c2 = 0.f, c3 = 0.f;
#pragma unroll 4
  for (int s = s0; s < s1; ++s) {
    const uint2* __restrict__ r =
        (const uint2*)(emb16 + (size_t)sid[wave][s] * EMB_DIM);
    uint2 v = r[lane];
    a0 += blo(v.x); a1 += bhi(v.x); a2 += blo(v.y); a3 += bhi(v.y);
    if (lane < 11) {
      uint2 w = r[64 + lane];
      c0 += blo(w.x); c1 += bhi(w.x); c2 += blo(w.y); c3 += bhi(w.y);
    }
  }
  const float sc = 1.0f / (float)SEQ;
  float4* __restrict__ xr = (float4*)(x + (size_t)b * EMB_DIM);
  if (first) {
    xr[lane] = make_float4(a0 * sc, a1 * sc, a2 * sc, a3 * sc);
    if (lane < 11) {
      float4* __restrict__ xb = (float4*)(x + (size_t)b * EMB_DIM + 256);
      xb[lane - 64 + 64] = make_float4(c0 * sc, c1 * sc, c2 * sc, c3 * sc);
    }
  } else {
    float4 prev = xr[lane];
    xr[lane] = make_float4(prev.x + a0 * sc, prev.y + a1 * sc,
                           prev.z + a2 * sc, prev.w + a3 * sc);
    if (lane < 11) {
      float4* __restrict__ xb = (float4*)(x + (size_t)b * EMB_DIM + 256);
      float4 pb = xb[lane];
      xb[lane] = make_float4(pb.x + c0 * sc, pb.y + c1 * sc,
                             pb.z + c2 * sc, pb.w + c3 * sc);
    }
  }
}

// ---------------------------------------------------------------------------
// Routed MLP, split-K: 4 waves = 2 groups x 2 K-halves. All register-array
// indices compile-time static (rule #20); kw-dependent paths via wave-uniform
// if/else; __syncthreads outside the branches.
// ---------------------------------------------------------------------------
__global__ __launch_bounds__(256) void mlp_kernel(
    const float* __restrict__ x, const int* __restrict__ aspect,
    const int* __restrict__ perm,
    const float* __restrict__ W1, const float* __restrict__ b1,
    const float* __restrict__ W2, const float* __restrict__ b2,
    float* __restrict__ out) {
  const int t = threadIdx.x;
  const int wave = t >> 6, lane = t & 63;
  const int g = wave >> 1;
  const int kw = wave & 1;
  const int start = blockIdx.x * MTILE;

  __shared__ int ss[MTILE];
  __shared__ float xch[2][8][64][4];

  if (t < MTILE) ss[t] = perm[start + t];
  __syncthreads();
  const int s0 = ss[0];
  if (s0 < 0) return;
  const int a = aspect[s0];

  int smp[8];
  const float* xrow[8];
#pragma unroll
  for (int s = 0; s < 8; ++s) {
    int m = __builtin_amdgcn_readfirstlane(ss[g * 8 + s]);
    smp[s] = m;
    xrow[s] = x + (size_t)(m < 0 ? s0 : m) * EMB_DIM;
  }

  const float4* __restrict__ w1r =
      (const float4*)(W1 + (size_t)a * EMB_DIM * HIDDEN) + lane;
  float4 acc[8];
  if (kw == 0) {
    const float4 bb = ((const float4*)(b1 + a * HIDDEN))[lane];
#pragma unroll
    for (int s = 0; s < 8; ++s) acc[s] = bb;
  } else {
#pragma unroll
    for (int s = 0; s < 8; ++s) acc[s] = make_float4(0.f, 0.f, 0.f, 0.f);
  }
  const int d0 = kw ? 160 : 0;
  const int d1 = kw ? EMB_DIM : 160;
  for (int d = d0; d < d1; d += 4) {
    float4 xv[8];
#pragma unroll
    for (int s = 0; s < 8; ++s) xv[s] = *(const float4*)(xrow[s] + d);
#pragma unroll
    for (int dd = 0; dd < 4; ++dd) {
      const float4 w = w1r[(size_t)(d + dd) * (HIDDEN / 4)];
#pragma unroll
      for (int s = 0; s < 8; ++s) {
        const float xs = dd == 0 ? xv[s].x : dd == 1 ? xv[s].y
                        : dd == 2 ? xv[s].z : xv[s].w;
        acc[s].x = fmaf(xs, w.x, acc[s].x);
        acc[s].y = fmaf(xs, w.y, acc[s].y);
        acc[s].z = fmaf(xs, w.z, acc[s].z);
        acc[s].w = fmaf(xs, w.w, acc[s].w);
      }
    }
  }

  if (kw == 0) {
#pragma unroll
    for (int i = 0; i < 4; ++i)
      *(float4*)&xch[g][4 + i][lane][0] = acc[4 + i];
  } else {
#pragma unroll
    for (int i = 0; i < 4; ++i)
      *(float4*)&xch[g][i][lane][0] = acc[i];
  }
  __syncthreads();

  const float4* __restrict__ w2p =
      (const float4*)(W2 + (size_t)a * HIDDEN * OUT_DIM + lane * 12);
  const float4 w2a = w2p[0];
  const float4 w2b = w2p[1];
  const float4 w2c = w2p[2];

  float4 own[4];
  int ms[4];
  if (kw == 0) {
    own[0] = acc[0]; own[1] = acc[1]; own[2] = acc[2]; own[3] = acc[3];
    ms[0] = smp[0]; ms[1] = smp[1]; ms[2] = smp[2]; ms[3] = smp[3];
  } else {
    own[0] = acc[4]; own[1] = acc[5]; own[2] = acc[6]; own[3] = acc[7];
    ms[0] = smp[4]; ms[1] = smp[5]; ms[2] = smp[6]; ms[3] = smp[7];
  }
  const int mys = 4 * kw;

  float p[4][OUT_DIM];
#pragma unroll
  for (int i = 0; i < 4; ++i) {
    const float4 pr = *(const float4*)&xch[g][mys + i][lane][0];
    const float h0 = fmaxf(own[i].x + pr.x, 0.f);
    const float h1 = fmaxf(own[i].y + pr.y, 0.f);
    const float h2 = fmaxf(own[i].z + pr.z, 0.f);
    const float h3 = fmaxf(own[i].w + pr.w, 0.f);
    p[i][0] = fmaf(h0, w2a.x, fmaf(h1, w2a.w, fmaf(h2, w2b.z, h3 * w2c.y)));
    p[i][1] = fmaf(h0, w2a.y, fmaf(h1, w2b.x, fmaf(h2, w2b.w, h3 * w2c.z)));
    p[i][2] = fmaf(h0, w2a.z, fmaf(h1, w2b.y, fmaf(h2, w2c.x, h3 * w2c.w)));
  }
#pragma unroll
  for (int off = 32; off > 0; off >>= 1)
#pragma unroll
    for (int i = 0; i < 4; ++i) {
      p[i][0] += __shfl_down(p[i][0], off);
      p[i][1] += __shfl_down(p[i][1], off);
      p[i][2] += __shfl_down(p[i][2], off);
    }

  if (lane == 0) {
    const float g0 = b2[a * OUT_DIM + 0];
    const float g1 = b2[a * OUT_DIM + 1];
    const float g2 = b2[a * OUT_DIM + 2];
#pragma unroll
    for (int i = 0; i < 4; ++i) {
      if (ms[i] >= 0) {
        float* o = out + (size_t)ms[i] * OUT_DIM;
        o[0] = p[i][0] + g0;
        o[1] = p[i][1] + g1;
        o[2] = p[i][2] + g2;
      }
    }
  }
}

// ---------------------------------------------------------------------------
extern "C" void kernel_launch(void* const* d_in, const int* in_sizes, int n_in,
                              void* d_out, int out_size, void* d_ws, size_t ws_size,
                              hipStream_t stream) {
  const int*   ids    = (const int*)d_in[0];
  const int*   aspect = (const int*)d_in[1];
  const float* emb    = (const float*)d_in[2];
  const float* W1     = (const float*)d_in[3];
  const float* b1     = (const float*)d_in[4];
  const float* W2     = (const float*)d_in[5];
  const float* b2     = (const float*)d_in[6];
  float*       out    = (float*)d_out;

  const int B     = in_sizes[1];
  const int nemb  = in_sizes[2];               // 15,000,000
  const int VOCAB = nemb / EMB_DIM;            // 50,000
  const int nblk  = (B + TILE - 1) / TILE + N_ASPECTS;
  const int nperm = nblk * TILE;

  // workspace: [x: B*300 f32][perm: nperm i32][emb16: nemb bf16]
  float* x    = (float*)d_ws;
  int*   perm = (int*)((char*)d_ws + (size_t)B * EMB_DIM * sizeof(float));
  unsigned short* emb16 =
      (unsigned short*)((char*)perm + (((size_t)nperm * 4 + 15) & ~(size_t)15));

  prep_kernel<<<513, 1024, 0, stream>>>(emb, (unsigned int*)emb16, nemb / 8,
                                        aspect, B, perm, nperm);
  const int vmid = VOCAB / 2;
  pool_kernel<<<(B + 3) / 4, 256, 0, stream>>>(ids, emb16, x, B,
                                               0, vmid, 1);
  pool_kernel<<<(B + 3) / 4, 256, 0, stream>>>(ids, emb16, x, B,
                                               vmid, 0x7fffffff, 0);
  mlp_kernel<<<nperm / MTILE, 256, 0, stream>>>(x, aspect, perm, W1, b1, W2, b2, out);
}

// Round 10
// 128.425 us; speedup vs baseline: 1.1404x; 1.1404x over previous
//
#include <hip/hip_runtime.h>

constexpr int EMB_DIM   = 300;
constexpr int HIDDEN    = 256;
constexpr int OUT_DIM   = 3;
constexpr int SEQ       = 128;
constexpr int N_ASPECTS = 8;
constexpr int TILE      = 32;    // bucket padding granularity
constexpr int MTILE     = 8;     // samples per MLP block (2 groups x 4)

// ---------------------------------------------------------------------------
// bf16 helpers (RNE)
// ---------------------------------------------------------------------------
__device__ __forceinline__ unsigned int bfbits(float f) {
  unsigned int u = __float_as_uint(f);
  return (u + 0x7fffu + ((u >> 16) & 1u)) >> 16;
}
__device__ __forceinline__ unsigned int pack2(float lo, float hi) {
  return bfbits(lo) | (bfbits(hi) << 16);
}
__device__ __forceinline__ float blo(unsigned int u) { return __uint_as_float(u << 16); }
__device__ __forceinline__ float bhi(unsigned int u) { return __uint_as_float(u & 0xffff0000u); }

// ---------------------------------------------------------------------------
// Fused prep: block 0 = deterministic counting-sort bucketing (pad to TILE,
// -1 = padding); blocks 1..N = fp32->bf16 table conversion (90 MB stream).
// ---------------------------------------------------------------------------
__global__ __launch_bounds__(1024) void prep_kernel(
    const float* __restrict__ emb, unsigned int* __restrict__ emb16, int n8,
    const int* __restrict__ aspect, int B, int* __restrict__ perm, int nperm) {
  const int t = threadIdx.x;

  if (blockIdx.x != 0) {
    int i = (blockIdx.x - 1) * 1024 + t;
    const int stride = (gridDim.x - 1) * 1024;
    for (; i < n8; i += stride) {
      const float4* p = (const float4*)emb + (size_t)i * 2;
      float4 a = p[0], b = p[1];
      uint4 o;
      o.x = pack2(a.x, a.y); o.y = pack2(a.z, a.w);
      o.z = pack2(b.x, b.y); o.w = pack2(b.z, b.w);
      ((uint4*)emb16)[i] = o;
    }
    return;
  }

  const int lane = t & 63, wave = t >> 6;          // 16 waves
  __shared__ int wcnt[16][N_ASPECTS];
  __shared__ int cur[16][N_ASPECTS];

  for (int i = t; i < nperm; i += 1024) perm[i] = -1;

  int my_a[8];
  int cnt[N_ASPECTS];
#pragma unroll
  for (int q = 0; q < N_ASPECTS; ++q) cnt[q] = 0;
#pragma unroll
  for (int k = 0; k < 8; ++k) {
    int s = t + k * 1024;
    int a = (s < B) ? aspect[s] : -1;
    my_a[k] = a;
#pragma unroll
    for (int q = 0; q < N_ASPECTS; ++q) cnt[q] += (a == q);
  }
#pragma unroll
  for (int q = 0; q < N_ASPECTS; ++q) {
    int c = cnt[q];
    for (int off = 32; off > 0; off >>= 1) c += __shfl_down(c, off);
    if (lane == 0) wcnt[wave][q] = c;
  }
  __syncthreads();
  if (t == 0) {
    int base = 0;
    for (int q = 0; q < N_ASPECTS; ++q) {
      int tot = 0;
      for (int w = 0; w < 16; ++w) { cur[w][q] = base + tot; tot += wcnt[w][q]; }
      base += ((tot + TILE - 1) / TILE) * TILE;
    }
  }
  __syncthreads();

#pragma unroll
  for (int k = 0; k < 8; ++k) {
    int a = my_a[k];
    int s = t + k * 1024;
#pragma unroll
    for (int q = 0; q < N_ASPECTS; ++q) {
      unsigned long long m = __ballot(a == q);
      if (a == q) {
        int rank = __popcll(m & ((1ull << lane) - 1ull));
        int pos = cur[wave][q] + rank;
        perm[pos] = s;
        if (rank == __popcll(m) - 1) cur[wave][q] = pos + 1;
      }
    }
  }
}

// ---------------------------------------------------------------------------
// Pool (R6 best-measured form): one sample per wave; bitonic-sort the ids so
// co-resident waves sweep the vocab in order (L2 convoy). uint2 bf16 loads.
// ---------------------------------------------------------------------------
__global__ __launch_bounds__(256) void pool_kernel(
    const int* __restrict__ ids, const unsigned short* __restrict__ emb16,
    float* __restrict__ x, int B) {
  const int wave = threadIdx.x >> 6, lane = threadIdx.x & 63;
  const int b = blockIdx.x * 4 + wave;
  if (b >= B) return;

  int r0 = ids[(size_t)b * SEQ + lane];
  int r1 = ids[(size_t)b * SEQ + lane + 64];

#pragma unroll
  for (int k = 2; k <= 128; k <<= 1) {
#pragma unroll
    for (int j = k >> 1; j >= 1; j >>= 1) {
      if (j == 64) {
        int lo = min(r0, r1), hi = max(r0, r1);
        r0 = lo; r1 = hi;
      } else {
        const bool up0 = ((lane & k) == 0);
        const bool up1 = (((lane + 64) & k) == 0);
        const bool side = ((lane & j) == 0);
        int o0 = __shfl_xor(r0, j);
        int o1 = __shfl_xor(r1, j);
        r0 = (side == up0) ? min(r0, o0) : max(r0, o0);
        r1 = (side == up1) ? min(r1, o1) : max(r1, o1);
      }
    }
  }

  __shared__ int sid[4][SEQ];
  sid[wave][lane]      = r0;
  sid[wave][lane + 64] = r1;
  __syncthreads();

  float a0 = 0.f, a1 = 0.f, a2 = 0.f, a3 = 0.f;
  float c0 = 0.f, c1 = 0.f, c2 = 0.f, c3 = 0.f;
#pragma unroll 4
  for (int s = 0; s < SEQ; ++s) {
    const uint2* __restrict__ r =
        (const uint2*)(emb16 + (size_t)sid[wave][s] * EMB_DIM);
    uint2 v = r[lane];
    a0 += blo(v.x); a1 += bhi(v.x); a2 += blo(v.y); a3 += bhi(v.y);
    if (lane < 11) {
      uint2 w = r[64 + lane];
      c0 += blo(w.x); c1 += bhi(w.x); c2 += blo(w.y); c3 += bhi(w.y);
    }
  }
  const float sc = 1.0f / (float)SEQ;
  float4* __restrict__ xr = (float4*)(x + (size_t)b * EMB_DIM);
  xr[lane] = make_float4(a0 * sc, a1 * sc, a2 * sc, a3 * sc);
  if (lane < 11)
    xr[64 + lane] = make_float4(c0 * sc, c1 * sc, c2 * sc, c3 * sc);
}

// ---------------------------------------------------------------------------
// Routed MLP, split-K, MTILE=8: 4 waves = 2 groups x 2 K-halves, 4 samples
// per group. Grid ~1056 blocks -> 4 blocks/CU = 4 waves/SIMD (R9 showed the
// MTILE=16 grid capped occupancy at 2/SIMD and exposed L2 latency).
// All register-array indices compile-time static (rule #20).
// ---------------------------------------------------------------------------
__global__ __launch_bounds__(256) void mlp_kernel(
    const float* __restrict__ x, const int* __restrict__ aspect,
    const int* __restrict__ perm,
    const float* __restrict__ W1, const float* __restrict__ b1,
    const float* __restrict__ W2, const float* __restrict__ b2,
    float* __restrict__ out) {
  const int t = threadIdx.x;
  const int wave = t >> 6, lane = t & 63;
  const int g = wave >> 1;                 // sample group 0/1
  const int kw = wave & 1;                 // K-half
  const int start = blockIdx.x * MTILE;

  __shared__ int ss[MTILE];
  __shared__ float xch[2][4][64][4];       // partner-half partials, 8 KB

  if (t < MTILE) ss[t] = perm[start + t];
  __syncthreads();
  const int s0 = ss[0];
  if (s0 < 0) return;                      // fully-padded block (uniform exit)
  const int a = aspect[s0];

  int smp[4];
  const float* xrow[4];
#pragma unroll
  for (int s = 0; s < 4; ++s) {
    int m = __builtin_amdgcn_readfirstlane(ss[g * 4 + s]);
    smp[s] = m;
    xrow[s] = x + (size_t)(m < 0 ? s0 : m) * EMB_DIM;
  }

  // layer 1 over this wave's K-range, 4 samples
  const float4* __restrict__ w1r =
      (const float4*)(W1 + (size_t)a * EMB_DIM * HIDDEN) + lane;
  float4 acc[4];
  if (kw == 0) {
    const float4 bb = ((const float4*)(b1 + a * HIDDEN))[lane];
#pragma unroll
    for (int s = 0; s < 4; ++s) acc[s] = bb;
  } else {
#pragma unroll
    for (int s = 0; s < 4; ++s) acc[s] = make_float4(0.f, 0.f, 0.f, 0.f);
  }
  const int d0 = kw ? 160 : 0;
  const int d1 = kw ? EMB_DIM : 160;
#pragma unroll 2
  for (int d = d0; d < d1; d += 4) {
    float4 xv[4];
#pragma unroll
    for (int s = 0; s < 4; ++s) xv[s] = *(const float4*)(xrow[s] + d);
#pragma unroll
    for (int dd = 0; dd < 4; ++dd) {
      const float4 w = w1r[(size_t)(d + dd) * (HIDDEN / 4)];
#pragma unroll
      for (int s = 0; s < 4; ++s) {
        const float xs = dd == 0 ? xv[s].x : dd == 1 ? xv[s].y
                        : dd == 2 ? xv[s].z : xv[s].w;
        acc[s].x = fmaf(xs, w.x, acc[s].x);
        acc[s].y = fmaf(xs, w.y, acc[s].y);
        acc[s].z = fmaf(xs, w.z, acc[s].z);
        acc[s].w = fmaf(xs, w.w, acc[s].w);
      }
    }
  }

  // hand the partner wave its 2 samples' partials (static indices per branch)
  if (kw == 0) {
    *(float4*)&xch[g][2][lane][0] = acc[2];
    *(float4*)&xch[g][3][lane][0] = acc[3];
  } else {
    *(float4*)&xch[g][0][lane][0] = acc[0];
    *(float4*)&xch[g][1][lane][0] = acc[1];
  }
  __syncthreads();

  // finish my 2 samples
  const float4* __restrict__ w2p =
      (const float4*)(W2 + (size_t)a * HIDDEN * OUT_DIM + lane * 12);
  const float4 w2a = w2p[0];   // j0k0 j0k1 j0k2 j1k0
  const float4 w2b = w2p[1];   // j1k1 j1k2 j2k0 j2k1
  const float4 w2c = w2p[2];   // j2k2 j3k0 j3k1 j3k2

  float4 own[2];
  int ms[2];
  if (kw == 0) {
    own[0] = acc[0]; own[1] = acc[1];
    ms[0] = smp[0];  ms[1] = smp[1];
  } else {
    own[0] = acc[2]; own[1] = acc[3];
    ms[0] = smp[2];  ms[1] = smp[3];
  }
  const int mys = 2 * kw;                  // LDS base (runtime ok)

  float p[2][OUT_DIM];
#pragma unroll
  for (int i = 0; i < 2; ++i) {
    const float4 pr = *(const float4*)&xch[g][mys + i][lane][0];
    const float h0 = fmaxf(own[i].x + pr.x, 0.f);
    const float h1 = fmaxf(own[i].y + pr.y, 0.f);
    const float h2 = fmaxf(own[i].z + pr.z, 0.f);
    const float h3 = fmaxf(own[i].w + pr.w, 0.f);
    p[i][0] = fmaf(h0, w2a.x, fmaf(h1, w2a.w, fmaf(h2, w2b.z, h3 * w2c.y)));
    p[i][1] = fmaf(h0, w2a.y, fmaf(h1, w2b.x, fmaf(h2, w2b.w, h3 * w2c.z)));
    p[i][2] = fmaf(h0, w2a.z, fmaf(h1, w2b.y, fmaf(h2, w2c.x, h3 * w2c.w)));
  }
#pragma unroll
  for (int off = 32; off > 0; off >>= 1)
#pragma unroll
    for (int i = 0; i < 2; ++i) {
      p[i][0] += __shfl_down(p[i][0], off);
      p[i][1] += __shfl_down(p[i][1], off);
      p[i][2] += __shfl_down(p[i][2], off);
    }

  if (lane == 0) {
    const float g0 = b2[a * OUT_DIM + 0];
    const float g1 = b2[a * OUT_DIM + 1];
    const float g2 = b2[a * OUT_DIM + 2];
#pragma unroll
    for (int i = 0; i < 2; ++i) {
      if (ms[i] >= 0) {
        float* o = out + (size_t)ms[i] * OUT_DIM;
        o[0] = p[i][0] + g0;
        o[1] = p[i][1] + g1;
        o[2] = p[i][2] + g2;
      }
    }
  }
}

// ---------------------------------------------------------------------------
extern "C" void kernel_launch(void* const* d_in, const int* in_sizes, int n_in,
                              void* d_out, int out_size, void* d_ws, size_t ws_size,
                              hipStream_t stream) {
  const int*   ids    = (const int*)d_in[0];
  const int*   aspect = (const int*)d_in[1];
  const float* emb    = (const float*)d_in[2];
  const float* W1     = (const float*)d_in[3];
  const float* b1     = (const float*)d_in[4];
  const float* W2     = (const float*)d_in[5];
  const float* b2     = (const float*)d_in[6];
  float*       out    = (float*)d_out;

  const int B     = in_sizes[1];
  const int nemb  = in_sizes[2];               // 15,000,000
  const int nblk  = (B + TILE - 1) / TILE + N_ASPECTS;
  const int nperm = nblk * TILE;               // multiple of 32 (and of MTILE)

  // workspace: [x: B*300 f32][perm: nperm i32][emb16: nemb bf16]
  float* x    = (float*)d_ws;
  int*   perm = (int*)((char*)d_ws + (size_t)B * EMB_DIM * sizeof(float));
  unsigned short* emb16 =
      (unsigned short*)((char*)perm + (((size_t)nperm * 4 + 15) & ~(size_t)15));

  prep_kernel<<<513, 1024, 0, stream>>>(emb, (unsigned int*)emb16, nemb / 8,
                                        aspect, B, perm, nperm);
  pool_kernel<<<(B + 3) / 4, 256, 0, stream>>>(ids, emb16, x, B);
  mlp_kernel<<<nperm / MTILE, 256, 0, stream>>>(x, aspect, perm, W1, b1, W2, b2, out);
}